// Round 3
// baseline (272.226 us; speedup 1.0000x reference)
//
#include <hip/hip_runtime.h>

// SelfAttentionHead R3: bf16 MFMA, transposed-attention restructure.
//  prep_w : W f32 -> WbT bf16 [192][1024]
//  qkv    : x f32 -> q,k row-major bf16 [32768][64]; v stored TRANSPOSED
//           vT bf16 [16][64][2048]. q pre-scaled by 0.125*log2(e).
//  attn   : single-wave blocks. S^T = K*Q^T (operand-swapped MFMA) so each
//           lane owns one q-row -> softmax = register reduce + 2 shuffles.
//           O^T = V^T * P^T with V^T frags loaded straight from global vT.
//           No __syncthreads anywhere; P^T via wave-private 2.3KB LDS strip.
// Fragment maps (m89/m91-verified): A[m=l15][k=Q*8+j] == B[k=Q*8+j][n=l15],
// C/D: col=l15, row=Q*4+reg. A/B lane-maps identical => operand swap = transpose.

typedef __bf16 bf16x8 __attribute__((ext_vector_type(8)));
typedef __bf16 bf16x4 __attribute__((ext_vector_type(4)));
typedef float f32x4 __attribute__((ext_vector_type(4)));

constexpr int kE = 1024;
constexpr int kH = 64;
constexpr int kT = 2048;
constexpr int kB = 16;
constexpr int kM = kB * kT;
constexpr float kQScale = 0.125f * 1.44269504088896340736f;  // H^-0.5 * log2(e)

#define MFMA16(a, b, c) __builtin_amdgcn_mfma_f32_16x16x32_bf16((a), (b), (c), 0, 0, 0)

// ---------------------------------------------------------------- prep_w
__global__ __launch_bounds__(256)
void prep_w(const float* __restrict__ Wq, const float* __restrict__ Wk,
            const float* __restrict__ Wv, __bf16* __restrict__ WbT)
{
    __shared__ float tl[64][65];
    const int mat = blockIdx.x >> 4;
    const int k0 = (blockIdx.x & 15) * 64;
    const float* src = (mat == 0) ? Wq : (mat == 1) ? Wk : Wv;

    const int t = threadIdx.x;
    const int kr = t >> 2;
    const int cg = (t & 3) * 16;
    #pragma unroll
    for (int i = 0; i < 4; ++i) {
        float4 v = *(const float4*)&src[(size_t)(k0 + kr) * kH + cg + 4 * i];
        tl[cg + 4 * i + 0][kr] = v.x;
        tl[cg + 4 * i + 1][kr] = v.y;
        tl[cg + 4 * i + 2][kr] = v.z;
        tl[cg + 4 * i + 3][kr] = v.w;
    }
    __syncthreads();
    const int nl = t >> 2;
    const int kg = (t & 3) * 16;
    bf16x8 o0, o1;
    #pragma unroll
    for (int j = 0; j < 8; ++j) {
        o0[j] = (__bf16)tl[nl][kg + j];
        o1[j] = (__bf16)tl[nl][kg + 8 + j];
    }
    *(bf16x8*)&WbT[(size_t)(mat * 64 + nl) * kE + k0 + kg] = o0;
    *(bf16x8*)&WbT[(size_t)(mat * 64 + nl) * kE + k0 + kg + 8] = o1;
}

// ---------------------------------------------------------------- qkv
// 512 blocks, 256 threads (4 waves). Block: 64 rows x 192 cols (q|k|v).
__global__ __launch_bounds__(256)
void qkv(const float* __restrict__ x, const __bf16* __restrict__ WbT,
         __bf16* __restrict__ qo, __bf16* __restrict__ ko, __bf16* __restrict__ vT)
{
    __shared__ __align__(16) __bf16 As[64][72];
    __shared__ __align__(16) __bf16 Bs[192][72];

    const int t = threadIdx.x;
    const int lane = t & 63;
    const int w = t >> 6;
    const int l15 = lane & 15;
    const int q = lane >> 4;
    const int row0 = blockIdx.x * 64;

    f32x4 acc[4][3];
    #pragma unroll
    for (int mt = 0; mt < 4; ++mt)
        #pragma unroll
        for (int nt = 0; nt < 3; ++nt) acc[mt][nt] = (f32x4){0.f, 0.f, 0.f, 0.f};

    const int sm = t >> 2;
    const int sc = (t & 3) * 16;

    for (int k0 = 0; k0 < kE; k0 += 64) {
        {   // stage A: f32 -> bf16
            float4 v0 = *(const float4*)&x[(size_t)(row0 + sm) * kE + k0 + sc];
            float4 v1 = *(const float4*)&x[(size_t)(row0 + sm) * kE + k0 + sc + 4];
            float4 v2 = *(const float4*)&x[(size_t)(row0 + sm) * kE + k0 + sc + 8];
            float4 v3 = *(const float4*)&x[(size_t)(row0 + sm) * kE + k0 + sc + 12];
            bf16x8 b0, b1;
            b0[0] = (__bf16)v0.x; b0[1] = (__bf16)v0.y; b0[2] = (__bf16)v0.z; b0[3] = (__bf16)v0.w;
            b0[4] = (__bf16)v1.x; b0[5] = (__bf16)v1.y; b0[6] = (__bf16)v1.z; b0[7] = (__bf16)v1.w;
            b1[0] = (__bf16)v2.x; b1[1] = (__bf16)v2.y; b1[2] = (__bf16)v2.z; b1[3] = (__bf16)v2.w;
            b1[4] = (__bf16)v3.x; b1[5] = (__bf16)v3.y; b1[6] = (__bf16)v3.z; b1[7] = (__bf16)v3.w;
            *(bf16x8*)&As[sm][sc] = b0;
            *(bf16x8*)&As[sm][sc + 8] = b1;
        }
        #pragma unroll
        for (int j = 0; j < 6; ++j) {   // stage B
            int id = t + 256 * j;
            int n = id >> 3;
            int kc = (id & 7) * 8;
            *(bf16x8*)&Bs[n][kc] = *(const bf16x8*)&WbT[(size_t)n * kE + k0 + kc];
        }
        __syncthreads();

        #pragma unroll
        for (int ks = 0; ks < 2; ++ks) {
            bf16x8 a4[4];
            #pragma unroll
            for (int mt = 0; mt < 4; ++mt)
                a4[mt] = *(const bf16x8*)&As[mt * 16 + l15][ks * 32 + q * 8];
            #pragma unroll
            for (int nt = 0; nt < 3; ++nt) {
                bf16x8 b = *(const bf16x8*)&Bs[w * 48 + nt * 16 + l15][ks * 32 + q * 8];
                #pragma unroll
                for (int mt = 0; mt < 4; ++mt)
                    acc[mt][nt] = MFMA16(a4[mt], b, acc[mt][nt]);
            }
        }
        __syncthreads();
    }

    const int batch = row0 >> 11;
    const int tr0 = row0 & 2047;
    #pragma unroll
    for (int nt = 0; nt < 3; ++nt) {
        const int col0 = w * 48 + nt * 16;
        const int mat = col0 >> 6;
        const int c = (col0 & 63) + l15;
        if (mat == 2) {
            // v: store transposed vT[batch][c][t]; 4 consecutive rows pack to b64
            #pragma unroll
            for (int mt = 0; mt < 4; ++mt) {
                const int trow = tr0 + mt * 16 + q * 4;
                bf16x4 pk;
                #pragma unroll
                for (int r = 0; r < 4; ++r) pk[r] = (__bf16)acc[mt][nt][r];
                *(bf16x4*)&vT[((size_t)batch * kH + c) * kT + trow] = pk;
            }
        } else {
            __bf16* dst = (mat == 0) ? qo : ko;
            const float sc_ = (mat == 0) ? kQScale : 1.0f;
            #pragma unroll
            for (int mt = 0; mt < 4; ++mt)
                #pragma unroll
                for (int r = 0; r < 4; ++r) {
                    const size_t row = row0 + mt * 16 + q * 4 + r;
                    dst[row * kH + c] = (__bf16)(acc[mt][nt][r] * sc_);
                }
        }
    }
}

// ---------------------------------------------------------------- attn
// 2048 single-wave blocks (64 thr). Block: 16 q-rows, cost-descending dispatch.
// Lane l15 owns q-row q16*16+l15 (all 4 quads cooperate across the s-dim).
__device__ __forceinline__ void load_kfrag(bf16x8 kf[8], const __bf16* kb,
                                           int s0, int l15, int Q)
{
    #pragma unroll
    for (int ks = 0; ks < 2; ++ks)
        #pragma unroll
        for (int nt = 0; nt < 4; ++nt)
            kf[ks * 4 + nt] =
                *(const bf16x8*)&kb[(size_t)(s0 + nt * 16 + l15) * kH + ks * 32 + Q * 8];
}

__global__ __launch_bounds__(64)
void attn(const __bf16* __restrict__ qm, const __bf16* __restrict__ km,
          const __bf16* __restrict__ vT, float* __restrict__ out)
{
    __shared__ __align__(16) __bf16 Ps[16][72];   // P^T strip: [q][s], wave-private

    const int lane = threadIdx.x;
    const int l15 = lane & 15;
    const int Q = lane >> 4;

    const int batch = blockIdx.x & 15;
    const int q16 = 127 - (blockIdx.x >> 4);      // long tasks dispatched first
    const int qrow = q16 * 16 + l15;
    const int last = q16 >> 2;

    const __bf16* qb = qm + (size_t)batch * kT * kH;
    const __bf16* kb = km + (size_t)batch * kT * kH;
    const __bf16* vb = vT + (size_t)batch * kH * kT;  // [h][s]

    // Q fragment (B-operand of S^T): B[k=h][n=q-row]
    bf16x8 aq[2];
    aq[0] = *(const bf16x8*)&qb[(size_t)qrow * kH + Q * 8];
    aq[1] = *(const bf16x8*)&qb[(size_t)qrow * kH + 32 + Q * 8];

    f32x4 O[4];
    #pragma unroll
    for (int i = 0; i < 4; ++i) O[i] = (f32x4){0.f, 0.f, 0.f, 0.f};
    float m_ = -3.0e38f, l_ = 0.f;

    bf16x8 kfa[8], kfb[8];
    load_kfrag(kfa, kb, 0, l15, Q);

    auto step = [&](bf16x8 (&kcur)[8], bf16x8 (&knxt)[8], int kt) {
        const int s0 = kt * 64;
        // V^T fragments (A-operand of O^T): contiguous global loads
        bf16x8 vf[8];
        #pragma unroll
        for (int ht = 0; ht < 4; ++ht)
            #pragma unroll
            for (int ss = 0; ss < 2; ++ss)
                vf[ht * 2 + ss] =
                    *(const bf16x8*)&vb[(size_t)(ht * 16 + l15) * kT + s0 + ss * 32 + Q * 8];
        if (kt < last) load_kfrag(knxt, kb, s0 + 64, l15, Q);   // prefetch

        // S^T = K * Q^T  (operand swap; lane owns q-col l15)
        f32x4 sacc[4];
        #pragma unroll
        for (int nt = 0; nt < 4; ++nt) sacc[nt] = (f32x4){0.f, 0.f, 0.f, 0.f};
        #pragma unroll
        for (int ks = 0; ks < 2; ++ks)
            #pragma unroll
            for (int nt = 0; nt < 4; ++nt)
                sacc[nt] = MFMA16(kcur[ks * 4 + nt], aq[ks], sacc[nt]);

        if (kt == last) {   // causal mask: s = s0+16nt+4Q+r, q = qrow
            #pragma unroll
            for (int nt = 0; nt < 4; ++nt)
                #pragma unroll
                for (int r = 0; r < 4; ++r)
                    if (s0 + nt * 16 + Q * 4 + r > qrow) sacc[nt][r] = -3.0e38f;
        }

        // online softmax: 15-op register max + 2 shuffles (quads hold disjoint s)
        float mx = sacc[0][0];
        #pragma unroll
        for (int nt = 0; nt < 4; ++nt)
            #pragma unroll
            for (int r = 0; r < 4; ++r) mx = fmaxf(mx, sacc[nt][r]);
        mx = fmaxf(mx, __shfl_xor(mx, 16));
        mx = fmaxf(mx, __shfl_xor(mx, 32));
        const float mnew = fmaxf(m_, mx);
        const float alpha = __builtin_amdgcn_exp2f(m_ - mnew);
        float rs = 0.f;
        #pragma unroll
        for (int nt = 0; nt < 4; ++nt)
            #pragma unroll
            for (int r = 0; r < 4; ++r) {
                const float p = __builtin_amdgcn_exp2f(sacc[nt][r] - mnew);
                sacc[nt][r] = p;
                rs += p;
            }
        rs += __shfl_xor(rs, 16);
        rs += __shfl_xor(rs, 32);
        l_ = l_ * alpha + rs;
        m_ = mnew;
        #pragma unroll
        for (int ht = 0; ht < 4; ++ht) O[ht] *= alpha;

        // P^T -> LDS (packed b64: s=16nt+4Q+(0..3) consecutive), wave-private
        #pragma unroll
        for (int nt = 0; nt < 4; ++nt) {
            bf16x4 pk;
            #pragma unroll
            for (int r = 0; r < 4; ++r) pk[r] = (__bf16)sacc[nt][r];
            *(bf16x4*)&Ps[l15][nt * 16 + Q * 4] = pk;
        }
        // P^T B-fragments: contiguous b128 reads (same-wave RAW: lgkmcnt by compiler)
        bf16x8 pb0 = *(const bf16x8*)&Ps[l15][Q * 8];
        bf16x8 pb1 = *(const bf16x8*)&Ps[l15][32 + Q * 8];

        // O^T += V^T * P^T
        #pragma unroll
        for (int ht = 0; ht < 4; ++ht) {
            O[ht] = MFMA16(vf[ht * 2 + 0], pb0, O[ht]);
            O[ht] = MFMA16(vf[ht * 2 + 1], pb1, O[ht]);
        }
    };

    for (int kt = 0; kt <= last; kt += 2) {
        step(kfa, kfb, kt);
        if (kt + 1 <= last) step(kfb, kfa, kt + 1);
    }

    // O^T C-layout: lane q-col=l15, h=16ht+4Q+r -> packed float4 stores
    const float inv = 1.0f / l_;
    float* orow = out + ((size_t)batch * kT + qrow) * kH;
    #pragma unroll
    for (int ht = 0; ht < 4; ++ht) {
        float4 o4;
        o4.x = O[ht][0] * inv; o4.y = O[ht][1] * inv;
        o4.z = O[ht][2] * inv; o4.w = O[ht][3] * inv;
        *(float4*)&orow[ht * 16 + Q * 4] = o4;
    }
}

extern "C" void kernel_launch(void* const* d_in, const int* in_sizes, int n_in,
                              void* d_out, int out_size, void* d_ws, size_t ws_size,
                              hipStream_t stream)
{
    (void)in_sizes; (void)n_in; (void)out_size; (void)ws_size;
    const float* x  = (const float*)d_in[0];
    const float* Wk = (const float*)d_in[1];
    const float* Wq = (const float*)d_in[2];
    const float* Wv = (const float*)d_in[3];

    __bf16* WbT = (__bf16*)d_ws;                       // 384 KiB
    __bf16* qb  = WbT + (size_t)192 * kE;              // 4 MiB each
    __bf16* kbuf = qb + (size_t)kM * kH;
    __bf16* vT   = kbuf + (size_t)kM * kH;

    prep_w<<<48, 256, 0, stream>>>(Wq, Wk, Wv, WbT);
    qkv<<<kM / 64, 256, 0, stream>>>(x, WbT, qb, kbuf, vT);
    attn<<<kB * 128, 64, 0, stream>>>(qb, kbuf, vT, (float*)d_out);
}